// Round 14
// baseline (2019.065 us; speedup 1.0000x reference)
//
#include <hip/hip_runtime.h>
#include <math.h>

#define SIDES 2
#define LAYERS 2
#define NTREE 8
#define NPT 1093
#define NN (NTREE*NPT)        // 8744
#define EE 256
#define HH 512
#define NUSERS 2000
#define NPOI 5000
#define NCAT 300
#define NCOO 50
#define FUSEN 5350
#define TMAXN 600
#define TOKMAX 5832           // 8*729
#define PARMAX 1944           // 8*243

constexpr long OUT_S   = 46780400L;   // per-side output block (floats)
constexpr long CAT_OFF = 43720000L;
constexpr long COO_OFF = 46343200L;

// element strides per side
constexpr long H_S    = (long)NN*HH;        // 4,476,928
constexpr long X_S    = (long)NN*EE;        // 2,238,464
constexpr long Z_S    = (long)TOKMAX*HH;    // 2,985,984
constexpr long QKV_S  = (long)TOKMAX*3*HH;  // 8,957,952
constexpr long WXI_S  = (long)PARMAX*2048;  // 3,981,312
constexpr long WEFF_S = (long)NPOI*HH;      // 2,560,000

typedef __attribute__((ext_vector_type(8))) short  bf16x8;
typedef __attribute__((ext_vector_type(8))) ushort u16x8;
typedef __attribute__((ext_vector_type(4))) ushort u16x4;
typedef __attribute__((ext_vector_type(4))) float  f32x4;

__device__ __forceinline__ float sigm(float x){ return 1.f/(1.f+expf(-x)); }
__device__ __forceinline__ ushort f2b(float f){
  union { float f; unsigned u; } v; v.f = f;
  return (ushort)((v.u + 0x7fffu + ((v.u >> 16) & 1u)) >> 16);
}
__device__ __forceinline__ float b2f(ushort u){
  union { unsigned u; float f; } v; v.u = (unsigned)u << 16; return v.f;
}

// ================= merged prep kernel (preconvert + embed) =================
constexpr int PB_EMB  = 2*NN;      // 17488
constexpr int PB_MCVT = 6494;
constexpr int PB_WCOMB= 2*2048;
constexpr int PB_BCOMB= 16;
constexpr int PB_POI  = 2*5000;
constexpr int PB_TP   = 2*512;
constexpr int PB_WEI  = 2*2500;
constexpr int PB_BEF  = 40;
constexpr int PB_TOT  = PB_EMB+PB_MCVT+PB_WCOMB+PB_BCOMB+PB_POI+PB_TP+PB_WEI+PB_BEF;

__global__ void __launch_bounds__(256) prep_k(
    const int* __restrict__ uid, const int* __restrict__ fid,
    const int* __restrict__ tids, const int* __restrict__ mask,
    const float* __restrict__ uemb, const float* __restrict__ femb,
    const float* __restrict__ tpe, ushort* __restrict__ X,
    ushort* ainW, const float* attn_in_w, ushort* aoutW, const float* attn_out_w,
    ushort* f1W, const float* ff1_w, ushort* f2W, const float* ff2_w,
    ushort* dcatW, const float* dec_cat_w, ushort* dcooW, const float* dec_coo_w,
    ushort* wcomb, const float* Wf, const float* Wiou, const float* Uiou,
    float* bcomb, const float* biou,
    ushort* c2pB, const float* cat2poi_w, ushort* o2pB, const float* coo2poi_w,
    ushort* dcT2,
    ushort* weffB, const float* dec_poi_w, const float* mtl,
    float* beff, const float* dec_poi_b, const float* dec_cat_b,
    const float* cat2poi_b, const float* dec_coo_b, const float* coo2poi_b){
  int b = blockIdx.x;
  int tid = threadIdx.x;
  if (b < PB_EMB){
    int s = b / NN; long i = b - s*NN; int d = tid;
    int m = mask[(long)s*NN + i];
    int u = uid[(long)s*NN + i]*m, f = fid[(long)s*NN + i]*m, t = tids[(long)s*NN + i]*m;
    float e = (d < 128) ? uemb[((long)s*NUSERS + u)*128 + d]
                        : femb[((long)s*FUSEN + f)*128 + (d-128)];
    e += 0.5f * tpe[((long)s*TMAXN + t)*256 + d];
    X[(long)s*X_S + i*EE + d] = f2b(e * (float)m);
    return;
  }
  b -= PB_EMB;
  if (b < PB_MCVT){
    const long n0 = 3145728, n1 = 1048576, n2 = 1048576, n3 = 1048576,
               n4 = 307200, n5 = 51200;
    long i = ((long)b*256 + tid)*4;
    ushort* d; const float* s; long off;
    if      (i < n0){ d=ainW;  s=attn_in_w;  off=i; }
    else if ((i-=n0) < n1){ d=aoutW; s=attn_out_w; off=i; }
    else if ((i-=n1) < n2){ d=f1W;  s=ff1_w;  off=i; }
    else if ((i-=n2) < n3){ d=f2W;  s=ff2_w;  off=i; }
    else if ((i-=n3) < n4){ d=dcatW; s=dec_cat_w; off=i; }
    else if ((i-=n4) < n5){ d=dcooW; s=dec_coo_w; off=i; }
    else return;
    f32x4 v = *(const f32x4*)(s + off);
    *(u16x4*)(d + off) = (u16x4){f2b(v[0]), f2b(v[1]), f2b(v[2]), f2b(v[3])};
    return;
  }
  b -= PB_MCVT;
  if (b < PB_WCOMB){
    int s = b >> 11; int row = b & 2047;
    ushort* dst = wcomb + (long)s*2048*1792 + (long)row*1792;
    for (int col = tid; col < 1792; col += 256){
      float v;
      if (row < 512) v = (col < 256) ? Wf[((long)s*512 + row)*256 + col] : 0.f;
      else {
        int r = row - 512;
        v = (col < 256) ? Wiou[((long)s*1536 + r)*256 + col]
                        : Uiou[((long)s*1536 + r)*1536 + (col-256)];
      }
      dst[col] = f2b(v);
    }
    return;
  }
  b -= PB_WCOMB;
  if (b < PB_BCOMB){
    int s = b >> 3; int c = (b & 7)*256 + tid;
    bcomb[(long)s*2048 + c] = (c < 512) ? 0.f : biou[(long)s*1536 + (c-512)];
    return;
  }
  b -= PB_BCOMB;
  if (b < PB_POI){
    int s = b / 5000; int r = b - s*5000;
    float a1 = 0.5f*expf(-mtl[(long)s*3 + 1]);
    float a2 = 0.5f*expf(-mtl[(long)s*3 + 2]);
    for (int c = tid; c < 320; c += 256){
      float v = (c < 300) ? a1*cat2poi_w[((long)s*5000 + r)*300 + c] : 0.f;
      c2pB[((long)s*5000 + r)*320 + c] = f2b(v);
    }
    if (tid < 64){
      float v = (tid < 50) ? a2*coo2poi_w[((long)s*5000 + r)*50 + tid] : 0.f;
      o2pB[((long)s*5000 + r)*64 + tid] = f2b(v);
    }
    return;
  }
  b -= PB_POI;
  if (b < PB_TP){
    // dcT2[512][384]: cols 0-319 = dec_cat^T (pad), cols 320-369 = dec_coo^T (pad)
    int s = b >> 9; int h = b & 511;
    ushort* dst = dcT2 + ((long)s*512 + h)*384;
    for (int c = tid; c < 384; c += 256){
      float v = 0.f;
      if (c < 300)                  v = dec_cat_w[((long)s*300 + c)*512 + h];
      else if (c >= 320 && c < 370) v = dec_coo_w[((long)s*50 + (c-320))*512 + h];
      dst[c] = f2b(v);
    }
    return;
  }
  b -= PB_TP;
  if (b < PB_WEI){
    int s = b / 2500; int blk = b - s*2500;
    long i = ((long)blk*256 + tid)*4;
    float a0 = 0.5f*expf(-mtl[(long)s*3]);
    f32x4 v = *(const f32x4*)(dec_poi_w + (long)s*WEFF_S + i);
    *(u16x4*)(weffB + (long)s*WEFF_S + i) =
        (u16x4){f2b(a0*v[0]), f2b(a0*v[1]), f2b(a0*v[2]), f2b(a0*v[3])};
    return;
  }
  b -= PB_WEI;
  {
    int s = b / 20; int n = (b - s*20)*256 + tid;
    if (n >= NPOI) return;
    const float* mt = mtl + (long)s*3;
    float a0 = 0.5f*expf(-mt[0]), a1 = 0.5f*expf(-mt[1]), a2 = 0.5f*expf(-mt[2]);
    float acc1 = 0.f, acc2 = 0.f;
    for (int c = 0; c < NCAT; c++)
      acc1 += dec_cat_b[(long)s*NCAT + c] * cat2poi_w[((long)s*NPOI + n)*NCAT + c];
    for (int c = 0; c < NCOO; c++)
      acc2 += dec_coo_b[(long)s*NCOO + c] * coo2poi_w[((long)s*NPOI + n)*NCOO + c];
    beff[(long)s*NPOI + n] = a0*dec_poi_b[(long)s*NPOI + n]
        + a1*(acc1 + cat2poi_b[(long)s*NPOI + n]) + a2*(acc2 + coo2poi_b[(long)s*NPOI + n])
        + mt[0] + mt[1] + mt[2];
  }
}

// ======== bf16 MFMA GEMM: BM=128 x BN=256, 4 waves, wave tile 128x64 ========
// MODE 0: store(+bias); 1: relu; 2: C += acc; 4: C += alpha*acc
template<int MODE, bool OBF>
__global__ void __launch_bounds__(256, 2)
mgemm_k(const ushort* __restrict__ A1, long lda1, long sA1,
        const ushort* __restrict__ A2, long lda2, long sA2,
        int kSplit, int mapN, int mapOff,
        const ushort* __restrict__ Wt, long ldw, long sW,
        const float* __restrict__ bias, long sB,
        void* __restrict__ Cv, long ldc, long sC,
        int M, int Nc, int K, int nbx,
        const float* __restrict__ mtl, int mtlIdx){
  int s = blockIdx.z;
  A1 += (long)s*sA1; A2 += (long)s*sA2; Wt += (long)s*sW;
  if (bias) bias += (long)s*sB;

  int flat = blockIdx.x, nwg = gridDim.x;
  int xcd = flat & 7, q = nwg >> 3, r8 = nwg & 7;
  int nf = (xcd < r8 ? xcd*(q+1) : r8*(q+1) + (xcd - r8)*q) + (flat >> 3);
  int bx = nf % nbx, by = nf / nbx;
  int m0 = by*128, n0 = bx*256;

  __shared__ ushort As[128*64];   // 16 KB
  __shared__ ushort Ws[256*64];   // 32 KB

  int tid = threadIdx.x;
  int lane = tid & 63, wave = tid >> 6;   // wave = N-slice index 0..3
  int fr = lane & 15, kc = lane >> 4;

  int baseRow = tid >> 3;
  int c16 = tid & 7;
  int col8 = c16*8;

  long gA1[4], gA2[4], gW[8];
  int abyte[4], wbyte[8];
  #pragma unroll
  for (int c = 0; c < 4; c++){
    int row = baseRow + c*32;
    int ra = m0 + row; if (ra > M-1) ra = M-1;
    gA2[c] = ra;
    if (mapN > 0){ int tr = ra / mapN; gA1[c] = (long)(tr*NPT + mapOff + (ra - tr*mapN)); }
    else gA1[c] = ra;
    abyte[c] = row*128 + ((c16*16) ^ ((row & 7) << 4));
  }
  #pragma unroll
  for (int c = 0; c < 8; c++){
    int row = baseRow + c*32;
    int rw = n0 + row; if (rw > Nc-1) rw = Nc-1;
    gW[c] = rw;
    wbyte[c] = row*128 + ((c16*16) ^ ((row & 7) << 4));
  }

  u16x8 rA[4], rW[8];
  {
    bool u1 = (0 < kSplit);
    const ushort* asrc = u1 ? A1 : A2;
    long ld = u1 ? lda1 : lda2;
    const long* g = u1 ? gA1 : gA2;
    #pragma unroll
    for (int c = 0; c < 4; c++)
      rA[c] = *(const u16x8*)(asrc + g[c]*ld + col8);
    #pragma unroll
    for (int c = 0; c < 8; c++)
      rW[c] = *(const u16x8*)(Wt + gW[c]*ldw + col8);
  }

  f32x4 acc[8][4];
  #pragma unroll
  for (int i = 0; i < 8; i++)
    #pragma unroll
    for (int j = 0; j < 4; j++) acc[i][j] = (f32x4){0.f,0.f,0.f,0.f};

  for (int k0 = 0; k0 < K; k0 += 64){
    #pragma unroll
    for (int c = 0; c < 4; c++)
      *(u16x8*)((char*)As + abyte[c]) = rA[c];
    #pragma unroll
    for (int c = 0; c < 8; c++)
      *(u16x8*)((char*)Ws + wbyte[c]) = rW[c];
    __syncthreads();
    int kn = k0 + 64;
    if (kn < K){
      bool u1 = (kn < kSplit);
      const ushort* asrc = u1 ? A1 : A2;
      long ld = u1 ? lda1 : lda2;
      const long* g = u1 ? gA1 : gA2;
      long colb = (u1 ? (long)kn : (long)(kn - kSplit)) + col8;
      #pragma unroll
      for (int c = 0; c < 4; c++)
        rA[c] = *(const u16x8*)(asrc + g[c]*ld + colb);
      #pragma unroll
      for (int c = 0; c < 8; c++)
        rW[c] = *(const u16x8*)(Wt + gW[c]*ldw + kn + col8);
    }
    #pragma unroll
    for (int h = 0; h < 2; h++){
      bf16x8 bw[4];
      #pragma unroll
      for (int j = 0; j < 4; j++){
        int row = wave*64 + j*16 + fr;
        int byo = row*128 + ((h*64 + kc*16) ^ ((row & 7) << 4));
        bw[j] = *(const bf16x8*)((const char*)Ws + byo);
      }
      #pragma unroll
      for (int i = 0; i < 8; i++){
        int row = i*16 + fr;
        int byo = row*128 + ((h*64 + kc*16) ^ ((row & 7) << 4));
        bf16x8 af = *(const bf16x8*)((const char*)As + byo);
        #pragma unroll
        for (int j = 0; j < 4; j++)
          acc[i][j] = __builtin_amdgcn_mfma_f32_16x16x32_bf16(bw[j], af, acc[i][j], 0, 0, 0);
      }
    }
    __syncthreads();
  }

  float alpha = 1.f;
  if (MODE == 4) alpha = 0.5f*expf(-mtl[(long)s*3 + mtlIdx]);
  int ccol = lane & 15, cr4 = (lane >> 4)*4;
  bool vecN = ((Nc & 3) == 0);
  float* Cf = (float*)Cv + (long)s*sC;
  ushort* Cb = (ushort*)Cv + (long)s*sC;
  #pragma unroll
  for (int i = 0; i < 8; i++){
    int gm = m0 + i*16 + ccol;
    if (gm >= M) continue;
    long rowoff = (long)gm*ldc;
    #pragma unroll
    for (int j = 0; j < 4; j++){
      int gn0 = n0 + wave*64 + j*16 + cr4;
      if (gn0 >= Nc) continue;
      f32x4 v = acc[i][j];
      if (MODE != 4 && MODE != 2 && bias){ f32x4 bv = *(const f32x4*)&bias[gn0]; v += bv; }
      if (MODE == 1){ v = (f32x4){fmaxf(v[0],0.f),fmaxf(v[1],0.f),fmaxf(v[2],0.f),fmaxf(v[3],0.f)}; }
      if (OBF){
        u16x4* cp = (u16x4*)&Cb[rowoff + gn0];
        if (MODE == 4 || MODE == 2){
          u16x4 o = *cp;
          float a = (MODE == 4) ? alpha : 1.f;
          *cp = (u16x4){f2b(b2f(o[0]) + a*v[0]), f2b(b2f(o[1]) + a*v[1]),
                        f2b(b2f(o[2]) + a*v[2]), f2b(b2f(o[3]) + a*v[3])};
        } else {
          *cp = (u16x4){f2b(v[0]), f2b(v[1]), f2b(v[2]), f2b(v[3])};
        }
      } else {
        if (vecN){
          f32x4* cp = (f32x4*)&Cf[rowoff + gn0];
          if (MODE == 4){ f32x4 o = *cp; *cp = o + alpha*v; }
          else if (MODE == 2){ f32x4 o = *cp; *cp = o + v; }
          else *cp = v;
        } else {
          #pragma unroll
          for (int r = 0; r < 4; r++){
            int gn = gn0 + r; if (gn >= Nc) continue;
            if (MODE == 4) Cf[rowoff + gn] += alpha*v[r];
            else if (MODE == 2) Cf[rowoff + gn] += v[r];
            else Cf[rowoff + gn] = v[r];
          }
        }
      }
    }
  }
}

// ================= 3x3 attention: one wave per (seq, head) =================
__global__ void __launch_bounds__(256) attn_k(const ushort* __restrict__ qkv,
                                              ushort* __restrict__ o){
  int s = blockIdx.z;
  int w = threadIdx.x >> 6, lane = threadIdx.x & 63;
  int seq = blockIdx.x*2 + (w >> 1);
  int h = w & 1;
  const ushort* base = qkv + (long)s*QKV_S + (long)seq*3*1536 + h*256 + lane*4;
  float q[3][4], k[3][4], v[3][4];
  #pragma unroll
  for (int i = 0; i < 3; i++){
    u16x4 tq = *(const u16x4*)(base + (long)i*1536);
    u16x4 tk = *(const u16x4*)(base + (long)i*1536 + 512);
    u16x4 tv = *(const u16x4*)(base + (long)i*1536 + 1024);
    #pragma unroll
    for (int e = 0; e < 4; e++){ q[i][e]=b2f(tq[e]); k[i][e]=b2f(tk[e]); v[i][e]=b2f(tv[e]); }
  }
  float p[9];
  #pragma unroll
  for (int i = 0; i < 3; i++)
    #pragma unroll
    for (int j = 0; j < 3; j++){
      float acc = 0.f;
      #pragma unroll
      for (int e = 0; e < 4; e++) acc += q[i][e]*k[j][e];
      p[i*3+j] = acc;
    }
  #pragma unroll
  for (int m = 1; m < 64; m <<= 1)
    #pragma unroll
    for (int t = 0; t < 9; t++) p[t] += __shfl_xor(p[t], m);
  float att[9];
  #pragma unroll
  for (int i = 0; i < 3; i++){
    float a = p[i*3]*0.0625f, bb = p[i*3+1]*0.0625f, c = p[i*3+2]*0.0625f;
    float mx = fmaxf(a, fmaxf(bb, c));
    a = expf(a-mx); bb = expf(bb-mx); c = expf(c-mx);
    float inv = 1.f/(a+bb+c);
    att[i*3] = a*inv; att[i*3+1] = bb*inv; att[i*3+2] = c*inv;
  }
  ushort* ob = o + (long)s*Z_S + (long)seq*1536 + h*256 + lane*4;
  #pragma unroll
  for (int i = 0; i < 3; i++){
    u16x4 r;
    #pragma unroll
    for (int e = 0; e < 4; e++)
      r[e] = f2b(att[i*3]*v[0][e] + att[i*3+1]*v[1][e] + att[i*3+2]*v[2][e]);
    *(u16x4*)(ob + (long)i*512) = r;
  }
}

// ================= z = LN(res + t): one wave per row =================
__global__ void __launch_bounds__(256) add_ln_k(ushort* __restrict__ zout, long sZ,
                         const ushort* __restrict__ res, long sR, int mapN, int mapOff,
                         const ushort* __restrict__ tb, long sT,
                         const float* __restrict__ w, const float* __restrict__ b,
                         long wstr){
  int s = blockIdx.z;
  int wv = threadIdx.x >> 6, lane = threadIdx.x & 63;
  int r = blockIdx.x*4 + wv;
  int g = r;
  if (mapN > 0){ int tr = r / mapN; g = tr*NPT + mapOff + (r - tr*mapN); }
  int d0 = lane*8;
  u16x8 rr = *(const u16x8*)(res + (long)s*sR + (long)g*HH + d0);
  u16x8 tt = *(const u16x8*)(tb  + (long)s*sT + (long)r*HH + d0);
  float x[8];
  float sum = 0.f;
  #pragma unroll
  for (int e = 0; e < 8; e++){ x[e] = b2f(rr[e]) + b2f(tt[e]); sum += x[e]; }
  #pragma unroll
  for (int m = 1; m < 64; m <<= 1) sum += __shfl_xor(sum, m);
  float mean = sum * (1.f/512.f);
  float vs = 0.f;
  #pragma unroll
  for (int e = 0; e < 8; e++){ float d = x[e]-mean; vs += d*d; }
  #pragma unroll
  for (int m = 1; m < 64; m <<= 1) vs += __shfl_xor(vs, m);
  float inv = 1.f/sqrtf(vs*(1.f/512.f) + 1e-5f);
  const float* wr_ = w + (long)s*wstr + d0;
  const float* br_ = b + (long)s*wstr + d0;
  f32x4 w0 = *(const f32x4*)wr_, w1 = *(const f32x4*)(wr_+4);
  f32x4 b0 = *(const f32x4*)br_, b1 = *(const f32x4*)(br_+4);
  u16x8 ov;
  #pragma unroll
  for (int e = 0; e < 4; e++){
    ov[e]   = f2b((x[e]-mean)*inv*w0[e] + b0[e]);
    ov[e+4] = f2b((x[e+4]-mean)*inv*w1[e] + b1[e]);
  }
  *(u16x8*)(zout + (long)s*sZ + (long)r*HH + d0) = ov;
}

// ================= leaf LSTM cell =================
__global__ void leaf_k(const ushort* __restrict__ iou, const float* __restrict__ c0,
                       ushort* __restrict__ hbuf, float* __restrict__ cbuf){
  int s = blockIdx.z, p = blockIdx.x;
  int tree = p / 729, j = p - tree*729;
  long row = (long)(tree*NPT + 364 + j)*HH;
  const ushort* iour = iou + (long)s*QKV_S + (long)p*1536;
  const float* c0r = c0 + (long)s*H_S + row;
  for (int d = threadIdx.x; d < HH; d += 256){
    float cn = sigm(b2f(iour[d])) * tanhf(b2f(iour[1024 + d])) + c0r[d];
    float hn = sigm(b2f(iour[512 + d])) * tanhf(cn);
    hbuf[(long)s*H_S + row + d] = f2b(hn);
    cbuf[(long)s*H_S + row + d] = cn;
  }
}

// ================= internal-node combine =================
__global__ void combine_k(const ushort* __restrict__ wxiou, const ushort* __restrict__ z,
                          const float* __restrict__ bfv, const float* __restrict__ cbuf,
                          ushort* __restrict__ hbuf, float* __restrict__ cout,
                          int n, int st, int cs){
  int s = blockIdx.z, p = blockIdx.x;
  int tree = p / n, j = p - tree*n;
  const ushort* wr_ = wxiou + (long)s*WXI_S + (long)p*2048;
  const ushort* zr  = z + (long)s*Z_S + (long)p*1536;
  const float* bfr  = bfv + (long)s*HH;
  const float* cch  = cbuf + (long)s*H_S + (long)(tree*NPT + cs + 3*j)*HH;
  long orow = (long)s*H_S + (long)(tree*NPT + st + j)*HH;
  for (int d = threadIdx.x; d < HH; d += 256){
    float wv = b2f(wr_[d]) + bfr[d];
    float cpre = 0.f;
    #pragma unroll
    for (int ch = 0; ch < 3; ch++){
      float fg = sigm(wv + b2f(zr[ch*512 + d]));
      cpre += fg * cch[ch*512 + d];
    }
    float iv = b2f(wr_[512 + d]), ov = b2f(wr_[1024 + d]), uv = b2f(wr_[1536 + d]);
    float cn = sigm(iv)*tanhf(uv) + cpre;
    float hn = sigm(ov)*tanhf(cn);
    hbuf[orow + d] = f2b(hn);
    cout[orow + d] = cn;
  }
}

// launch helpers (BN = 256 now)
#define GEMM(MODE, OBF, A1, LDA1, SA1, A2, LDA2, SA2, KSPL, MAPN, MAPOFF, WT, LDW, SW, \
             BI, SB, CC, LDC, SC, M, NC, K)                                            \
  do { int nbx_ = ((NC)+255)/256, nby_ = ((M)+127)/128;                                \
    mgemm_k<MODE, OBF><<<dim3(nbx_*nby_, 1, SIDES), 256, 0, stream>>>(                 \
      A1, LDA1, SA1, A2, LDA2, SA2, KSPL, MAPN, MAPOFF, WT, LDW, SW, BI, SB,           \
      CC, LDC, SC, M, NC, K, nbx_, mtl, 0); } while(0)

extern "C" void kernel_launch(void* const* d_in, const int* in_sizes, int n_in,
                              void* d_out, int out_size, void* d_ws, size_t ws_size,
                              hipStream_t stream){
  (void)in_sizes; (void)n_in; (void)out_size; (void)ws_size;
  const int*   user_ids  = (const int*)d_in[0];
  const int*   feat_ids  = (const int*)d_in[1];
  const int*   time_ids  = (const int*)d_in[2];
  const int*   mask      = (const int*)d_in[3];
  const float* user_emb  = (const float*)d_in[6];
  const float* fuse_emb  = (const float*)d_in[7];
  const float* time_pe   = (const float*)d_in[8];
  const float* Wf        = (const float*)d_in[9];
  const float* bf        = (const float*)d_in[10];
  const float* Wiou      = (const float*)d_in[11];
  const float* Uiou      = (const float*)d_in[12];
  const float* biou      = (const float*)d_in[13];
  const float* attn_in_w = (const float*)d_in[14];
  const float* attn_in_b = (const float*)d_in[15];
  const float* attn_out_w= (const float*)d_in[16];
  const float* attn_out_b= (const float*)d_in[17];
  const float* ff1_w     = (const float*)d_in[18];
  const float* ff1_b     = (const float*)d_in[19];
  const float* ff2_w     = (const float*)d_in[20];
  const float* ff2_b     = (const float*)d_in[21];
  const float* ln1_w     = (const float*)d_in[22];
  const float* ln1_b     = (const float*)d_in[23];
  const float* ln2_w     = (const float*)d_in[24];
  const float* ln2_b     = (const float*)d_in[25];
  const float* dec_poi_w = (const float*)d_in[26];
  const float* dec_poi_b = (const float*)d_in[27];
  const float* dec_cat_w = (const float*)d_in[28];
  const float* dec_cat_b = (const float*)d_in[29];
  const float* dec_coo_w = (const float*)d_in[30];
  const float* dec_coo_b = (const float*)d_in[31];
  const float* cat2poi_w = (const float*)d_in[32];
  const float* cat2poi_b = (const float*)d_in[33];
  const float* coo2poi_w = (const float*)d_in[34];
  const float* coo2poi_b = (const float*)d_in[35];
  const float* mtl       = (const float*)d_in[36];
  const float* c0        = (const float*)d_in[37];

  float* out = (float*)d_out;

  // ---- ws layout (bf16 persistent: Hb, weights) ----
  ushort* wsu = (ushort*)d_ws;
  ushort* Hb    = wsu;                         // [2][NN*512]
  ushort* ainW  = Hb    + 2*H_S;               // [2][2][1536*512]
  ushort* aoutW = ainW  + (long)2*2*1536*512;  // [2][2][512*512]
  ushort* f1W   = aoutW + (long)2*2*512*512;
  ushort* f2W   = f1W   + (long)2*2*512*512;
  ushort* wcomb = f2W   + (long)2*2*512*512;   // [2][2048*1792]
  ushort* dcatW = wcomb + (long)2*2048*1792;   // [2][300*512]
  ushort* dcooW = dcatW + (long)2*300*512;     // [2][50*512]
  ushort* weffB = dcooW + (long)2*50*512;      // [2][5000*512]
  float*  bcomb = (float*)(weffB + (long)2*WEFF_S);  // [2][2048]
  float*  beff  = bcomb + 2*2048;              // [2][5000]

  // ---- out-scratch (side-1 poi region; dead before final GEMM writes it) ----
  float*  Cb   = out + OUT_S;                  // [2][NN*512] f32
  ushort* osu  = (ushort*)(Cb + 2*H_S);
  ushort* QKV  = osu;                          // [2][TOKMAX*1536]
  ushort* Zb   = QKV  + 2*QKV_S;               // [2][TOKMAX*512]
  ushort* TMP  = Zb   + 2*Z_S;
  ushort* WXI  = TMP  + 2*Z_S;                 // [2][PARMAX*2048]
  ushort* Xb   = WXI  + 2*WXI_S;               // [2][NN*256]
  ushort* c2pB = Xb   + 2*X_S;                 // [2][5000*320]
  ushort* o2pB = c2pB + (long)2*5000*320;      // [2][5000*64]
  ushort* dcT2 = o2pB + (long)2*5000*64;       // [2][512*384]

  // ---- merged prep (preconvert + embed) ----
  prep_k<<<dim3(PB_TOT), 256, 0, stream>>>(
      user_ids, feat_ids, time_ids, mask, user_emb, fuse_emb, time_pe, Xb,
      ainW, attn_in_w, aoutW, attn_out_w, f1W, ff1_w, f2W, ff2_w,
      dcatW, dec_cat_w, dcooW, dec_coo_w,
      wcomb, Wf, Wiou, Uiou, bcomb, biou,
      c2pB, cat2poi_w, o2pB, coo2poi_w, dcT2,
      weffB, dec_poi_w, mtl,
      beff, dec_poi_b, dec_cat_b, cat2poi_b, dec_coo_b, coo2poi_b);

  // ---- leaves ----
  GEMM(0, true, Xb, 256L, X_S, Xb, 256L, X_S, 256, 729, 364,
       wcomb + (long)512*1792, 1792L, (long)2048*1792,
       (const float*)nullptr, 0L, QKV, 1536L, QKV_S, 5832, 1536, 256);
  leaf_k<<<dim3(5832, 1, SIDES), 256, 0, stream>>>(QKV, c0, Hb, Cb);

  const int p3[7]   = {1,3,9,27,81,243,729};
  const int offs[7] = {0,1,4,13,40,121,364};

  // ---- internal levels ----
  for (int l = 5; l >= 0; l--){
    int n = p3[l], st = offs[l], cs = offs[l+1];
    int P = NTREE*n, T = 3*P;
    for (int L = 0; L < LAYERS; L++){
      const ushort* zin = (L == 0) ? Hb : Zb;
      long zs = (L == 0) ? H_S : Z_S;
      int mN = (L == 0) ? 3*n : 0, mO = (L == 0) ? cs : 0;
      GEMM(0, true, zin, 512L, zs, zin, 512L, zs, 512, mN, mO,
           ainW + (long)L*1536*512, 512L, (long)2*1536*512,
           attn_in_b + (long)L*1536, (long)LAYERS*1536, QKV, 1536L, QKV_S, T, 1536, 512);
      attn_k<<<dim3(P/2, 1, SIDES), 256, 0, stream>>>(QKV, TMP);
      GEMM(0, true, TMP, 512L, Z_S, TMP, 512L, Z_S, 512, 0, 0,
           aoutW + (long)L*512*512, 512L, (long)2*512*512,
           attn_out_b + (long)L*512, (long)LAYERS*512, QKV, 512L, QKV_S, T, 512, 512);
      add_ln_k<<<dim3(T/4, 1, SIDES), 256, 0, stream>>>(Zb, Z_S, zin, zs, mN, mO,
           QKV, QKV_S, ln1_w + (long)L*512, ln1_b + (long)L*512, (long)LAYERS*512);
      GEMM(1, true, Zb, 512L, Z_S, Zb, 512L, Z_S, 512, 0, 0,
           f1W + (long)L*512*512, 512L, (long)2*512*512,
           ff1_b + (long)L*512, (long)LAYERS*512, TMP, 512L, Z_S, T, 512, 512);
      GEMM(0, true, TMP, 512L, Z_S, TMP, 512L, Z_S, 512, 0, 0,
           f2W + (long)L*512*512, 512L, (long)2*512*512,
           ff2_b + (long)L*512, (long)LAYERS*512, QKV, 512L, QKV_S, T, 512, 512);
      add_ln_k<<<dim3(T/4, 1, SIDES), 256, 0, stream>>>(Zb, Z_S, Zb, Z_S, 0, 0,
           QKV, QKV_S, ln2_w + (long)L*512, ln2_b + (long)L*512, (long)LAYERS*512);
    }
    // [wx | iou] = [x | z] @ [Wf|0 ; Wiou|Uiou]^T + [0|biou]
    GEMM(0, true, Xb, 256L, X_S, Zb, 1536L, Z_S, 256, n, st,
         wcomb, 1792L, (long)2048*1792, bcomb, 2048L, WXI, 2048L, WXI_S, P, 2048, 1792);
    combine_k<<<dim3(P, 1, SIDES), 256, 0, stream>>>(WXI, Zb, bf, Cb, Hb, Cb, n, st, cs);
  }

  // ---- cat/coo decoders ----
  GEMM(0, false, Hb, 512L, H_S, Hb, 512L, H_S, 512, 0, 0,
       dcatW, 512L, (long)NCAT*512, dec_cat_b, (long)NCAT,
       out + CAT_OFF, (long)NCAT, OUT_S, NN, NCAT, 512);
  GEMM(0, false, Hb, 512L, H_S, Hb, 512L, H_S, 512, 0, 0,
       dcooW, 512L, (long)NCOO*512, dec_coo_b, (long)NCOO,
       out + COO_OFF, (long)NCOO, OUT_S, NN, NCOO, 512);

  // ---- Weff += a1*cat2poi@dec_cat^T + a2*coo2poi@dec_coo^T (one dual-source GEMM) ----
  GEMM(2, true, c2pB, 320L, (long)5000*320, o2pB, 64L, (long)5000*64, 320, 0, 0,
       dcT2, 384L, (long)512*384, (const float*)nullptr, 0L,
       weffB, 512L, WEFF_S, 5000, 512, 384);

  // ---- fused poi decoder ----
  GEMM(0, false, Hb, 512L, H_S, Hb, 512L, H_S, 512, 0, 0,
       weffB, 512L, WEFF_S, beff, (long)NPOI,
       out, (long)NPOI, OUT_S, NN, NPOI, 512);
}

// Round 15
// 1553.847 us; speedup vs baseline: 1.2994x; 1.2994x over previous
//
#include <hip/hip_runtime.h>
#include <math.h>

#define SIDES 2
#define LAYERS 2
#define NTREE 8
#define NPT 1093
#define NN (NTREE*NPT)        // 8744
#define EE 256
#define HH 512
#define NUSERS 2000
#define NPOI 5000
#define NCAT 300
#define NCOO 50
#define FUSEN 5350
#define TMAXN 600
#define TOKMAX 5832           // 8*729
#define PARMAX 1944           // 8*243

constexpr long OUT_S   = 46780400L;   // per-side output block (floats)
constexpr long CAT_OFF = 43720000L;
constexpr long COO_OFF = 46343200L;

// element strides per side
constexpr long H_S    = (long)NN*HH;        // 4,476,928
constexpr long X_S    = (long)NN*EE;        // 2,238,464
constexpr long Z_S    = (long)TOKMAX*HH;    // 2,985,984
constexpr long QKV_S  = (long)TOKMAX*3*HH;  // 8,957,952
constexpr long WXI_S  = (long)PARMAX*2048;  // 3,981,312
constexpr long WEFF_S = (long)NPOI*HH;      // 2,560,000

typedef __attribute__((ext_vector_type(8))) short  bf16x8;
typedef __attribute__((ext_vector_type(8))) ushort u16x8;
typedef __attribute__((ext_vector_type(4))) ushort u16x4;
typedef __attribute__((ext_vector_type(4))) float  f32x4;

__device__ __forceinline__ float sigm(float x){ return 1.f/(1.f+expf(-x)); }
__device__ __forceinline__ ushort f2b(float f){
  union { float f; unsigned u; } v; v.f = f;
  return (ushort)((v.u + 0x7fffu + ((v.u >> 16) & 1u)) >> 16);
}
__device__ __forceinline__ float b2f(ushort u){
  union { unsigned u; float f; } v; v.u = (unsigned)u << 16; return v.f;
}

// ================= merged prep kernel (preconvert + embed) =================
constexpr int PB_EMB  = 2*NN;      // 17488
constexpr int PB_MCVT = 6494;
constexpr int PB_WCOMB= 2*2048;
constexpr int PB_BCOMB= 16;
constexpr int PB_POI  = 2*5000;
constexpr int PB_TP   = 2*512;
constexpr int PB_WEI  = 2*2500;
constexpr int PB_BEF  = 40;
constexpr int PB_TOT  = PB_EMB+PB_MCVT+PB_WCOMB+PB_BCOMB+PB_POI+PB_TP+PB_WEI+PB_BEF;

__global__ void __launch_bounds__(256) prep_k(
    const int* __restrict__ uid, const int* __restrict__ fid,
    const int* __restrict__ tids, const int* __restrict__ mask,
    const float* __restrict__ uemb, const float* __restrict__ femb,
    const float* __restrict__ tpe, ushort* __restrict__ X,
    ushort* ainW, const float* attn_in_w, ushort* aoutW, const float* attn_out_w,
    ushort* f1W, const float* ff1_w, ushort* f2W, const float* ff2_w,
    ushort* dcatW, const float* dec_cat_w, ushort* dcooW, const float* dec_coo_w,
    ushort* wcomb, const float* Wf, const float* Wiou, const float* Uiou,
    float* bcomb, const float* biou,
    ushort* c2pB, const float* cat2poi_w, ushort* o2pB, const float* coo2poi_w,
    ushort* dcT2,
    ushort* weffB, const float* dec_poi_w, const float* mtl,
    float* beff, const float* dec_poi_b, const float* dec_cat_b,
    const float* cat2poi_b, const float* dec_coo_b, const float* coo2poi_b){
  int b = blockIdx.x;
  int tid = threadIdx.x;
  if (b < PB_EMB){
    int s = b / NN; long i = b - s*NN; int d = tid;
    int m = mask[(long)s*NN + i];
    int u = uid[(long)s*NN + i]*m, f = fid[(long)s*NN + i]*m, t = tids[(long)s*NN + i]*m;
    float e = (d < 128) ? uemb[((long)s*NUSERS + u)*128 + d]
                        : femb[((long)s*FUSEN + f)*128 + (d-128)];
    e += 0.5f * tpe[((long)s*TMAXN + t)*256 + d];
    X[(long)s*X_S + i*EE + d] = f2b(e * (float)m);
    return;
  }
  b -= PB_EMB;
  if (b < PB_MCVT){
    const long n0 = 3145728, n1 = 1048576, n2 = 1048576, n3 = 1048576,
               n4 = 307200, n5 = 51200;
    long i = ((long)b*256 + tid)*4;
    ushort* d; const float* s; long off;
    if      (i < n0){ d=ainW;  s=attn_in_w;  off=i; }
    else if ((i-=n0) < n1){ d=aoutW; s=attn_out_w; off=i; }
    else if ((i-=n1) < n2){ d=f1W;  s=ff1_w;  off=i; }
    else if ((i-=n2) < n3){ d=f2W;  s=ff2_w;  off=i; }
    else if ((i-=n3) < n4){ d=dcatW; s=dec_cat_w; off=i; }
    else if ((i-=n4) < n5){ d=dcooW; s=dec_coo_w; off=i; }
    else return;
    f32x4 v = *(const f32x4*)(s + off);
    *(u16x4*)(d + off) = (u16x4){f2b(v[0]), f2b(v[1]), f2b(v[2]), f2b(v[3])};
    return;
  }
  b -= PB_MCVT;
  if (b < PB_WCOMB){
    int s = b >> 11; int row = b & 2047;
    ushort* dst = wcomb + (long)s*2048*1792 + (long)row*1792;
    for (int col = tid; col < 1792; col += 256){
      float v;
      if (row < 512) v = (col < 256) ? Wf[((long)s*512 + row)*256 + col] : 0.f;
      else {
        int r = row - 512;
        v = (col < 256) ? Wiou[((long)s*1536 + r)*256 + col]
                        : Uiou[((long)s*1536 + r)*1536 + (col-256)];
      }
      dst[col] = f2b(v);
    }
    return;
  }
  b -= PB_WCOMB;
  if (b < PB_BCOMB){
    int s = b >> 3; int c = (b & 7)*256 + tid;
    bcomb[(long)s*2048 + c] = (c < 512) ? 0.f : biou[(long)s*1536 + (c-512)];
    return;
  }
  b -= PB_BCOMB;
  if (b < PB_POI){
    int s = b / 5000; int r = b - s*5000;
    float a1 = 0.5f*expf(-mtl[(long)s*3 + 1]);
    float a2 = 0.5f*expf(-mtl[(long)s*3 + 2]);
    for (int c = tid; c < 320; c += 256){
      float v = (c < 300) ? a1*cat2poi_w[((long)s*5000 + r)*300 + c] : 0.f;
      c2pB[((long)s*5000 + r)*320 + c] = f2b(v);
    }
    if (tid < 64){
      float v = (tid < 50) ? a2*coo2poi_w[((long)s*5000 + r)*50 + tid] : 0.f;
      o2pB[((long)s*5000 + r)*64 + tid] = f2b(v);
    }
    return;
  }
  b -= PB_POI;
  if (b < PB_TP){
    // dcT2[512][384]: cols 0-319 = dec_cat^T (pad), cols 320-369 = dec_coo^T (pad)
    int s = b >> 9; int h = b & 511;
    ushort* dst = dcT2 + ((long)s*512 + h)*384;
    for (int c = tid; c < 384; c += 256){
      float v = 0.f;
      if (c < 300)                  v = dec_cat_w[((long)s*300 + c)*512 + h];
      else if (c >= 320 && c < 370) v = dec_coo_w[((long)s*50 + (c-320))*512 + h];
      dst[c] = f2b(v);
    }
    return;
  }
  b -= PB_TP;
  if (b < PB_WEI){
    int s = b / 2500; int blk = b - s*2500;
    long i = ((long)blk*256 + tid)*4;
    float a0 = 0.5f*expf(-mtl[(long)s*3]);
    f32x4 v = *(const f32x4*)(dec_poi_w + (long)s*WEFF_S + i);
    *(u16x4*)(weffB + (long)s*WEFF_S + i) =
        (u16x4){f2b(a0*v[0]), f2b(a0*v[1]), f2b(a0*v[2]), f2b(a0*v[3])};
    return;
  }
  b -= PB_WEI;
  {
    int s = b / 20; int n = (b - s*20)*256 + tid;
    if (n >= NPOI) return;
    const float* mt = mtl + (long)s*3;
    float a0 = 0.5f*expf(-mt[0]), a1 = 0.5f*expf(-mt[1]), a2 = 0.5f*expf(-mt[2]);
    float acc1 = 0.f, acc2 = 0.f;
    for (int c = 0; c < NCAT; c++)
      acc1 += dec_cat_b[(long)s*NCAT + c] * cat2poi_w[((long)s*NPOI + n)*NCAT + c];
    for (int c = 0; c < NCOO; c++)
      acc2 += dec_coo_b[(long)s*NCOO + c] * coo2poi_w[((long)s*NPOI + n)*NCOO + c];
    beff[(long)s*NPOI + n] = a0*dec_poi_b[(long)s*NPOI + n]
        + a1*(acc1 + cat2poi_b[(long)s*NPOI + n]) + a2*(acc2 + coo2poi_b[(long)s*NPOI + n])
        + mt[0] + mt[1] + mt[2];
  }
}

// ================= bf16 MFMA GEMM (reg-staged, swizzled LDS) =================
// MODE 0: store(+bias); 1: relu; 2: C += acc; 4: C += alpha*acc
template<int MODE, bool OBF>
__global__ void __launch_bounds__(256)
mgemm_k(const ushort* __restrict__ A1, long lda1, long sA1,
        const ushort* __restrict__ A2, long lda2, long sA2,
        int kSplit, int mapN, int mapOff,
        const ushort* __restrict__ Wt, long ldw, long sW,
        const float* __restrict__ bias, long sB,
        void* __restrict__ Cv, long ldc, long sC,
        int M, int Nc, int K, int nbx,
        const float* __restrict__ mtl, int mtlIdx){
  int s = blockIdx.z;
  A1 += (long)s*sA1; A2 += (long)s*sA2; Wt += (long)s*sW;
  if (bias) bias += (long)s*sB;

  int flat = blockIdx.x, nwg = gridDim.x;
  int xcd = flat & 7, q = nwg >> 3, r8 = nwg & 7;
  int nf = (xcd < r8 ? xcd*(q+1) : r8*(q+1) + (xcd - r8)*q) + (flat >> 3);
  int bx = nf % nbx, by = nf / nbx;
  int m0 = by*128, n0 = bx*128;

  __shared__ ushort As[128*64];
  __shared__ ushort Ws[128*64];

  int tid = threadIdx.x;
  int lane = tid & 63, wave = tid >> 6;
  int wr = wave >> 1, wc = wave & 1;
  int fr = lane & 15, kc = lane >> 4;

  int baseRow = tid >> 3;
  int c16 = tid & 7;
  int col8 = c16*8;
  int swz = (baseRow & 7) << 4;

  long gA1[4], gA2[4], gW[4];
  int wbyte[4];
  #pragma unroll
  for (int c = 0; c < 4; c++){
    int row = baseRow + c*32;
    int ra = m0 + row; if (ra > M-1) ra = M-1;
    gA2[c] = ra;
    if (mapN > 0){ int tr = ra / mapN; gA1[c] = (long)(tr*NPT + mapOff + (ra - tr*mapN)); }
    else gA1[c] = ra;
    int rw = n0 + row; if (rw > Nc-1) rw = Nc-1;
    gW[c] = rw;
    wbyte[c] = row*128 + ((c16*16) ^ swz);
  }

  u16x8 rA[4], rW[4];
  {
    bool u1 = (0 < kSplit);
    const ushort* asrc = u1 ? A1 : A2;
    long ld = u1 ? lda1 : lda2;
    const long* g = u1 ? gA1 : gA2;
    #pragma unroll
    for (int c = 0; c < 4; c++){
      rA[c] = *(const u16x8*)(asrc + g[c]*ld + col8);
      rW[c] = *(const u16x8*)(Wt + gW[c]*ldw + col8);
    }
  }

  f32x4 acc[4][4];
  #pragma unroll
  for (int i = 0; i < 4; i++)
    #pragma unroll
    for (int j = 0; j < 4; j++) acc[i][j] = (f32x4){0.f,0.f,0.f,0.f};

  for (int k0 = 0; k0 < K; k0 += 64){
    #pragma unroll
    for (int c = 0; c < 4; c++){
      *(u16x8*)((char*)As + wbyte[c]) = rA[c];
      *(u16x8*)((char*)Ws + wbyte[c]) = rW[c];
    }
    __syncthreads();
    int kn = k0 + 64;
    if (kn < K){
      bool u1 = (kn < kSplit);
      const ushort* asrc = u1 ? A1 : A2;
      long ld = u1 ? lda1 : lda2;
      const long* g = u1 ? gA1 : gA2;
      long colb = u1 ? (long)kn : (long)(kn - kSplit);
      #pragma unroll
      for (int c = 0; c < 4; c++){
        rA[c] = *(const u16x8*)(asrc + g[c]*ld + colb + col8);
        rW[c] = *(const u16x8*)(Wt + gW[c]*ldw + kn + col8);
      }
    }
    #pragma unroll
    for (int h = 0; h < 2; h++){
      bf16x8 af[4], bw[4];
      #pragma unroll
      for (int i = 0; i < 4; i++){
        int row = wr*64 + i*16 + fr;
        int byo = row*128 + ((h*64 + kc*16) ^ ((row & 7) << 4));
        af[i] = *(const bf16x8*)((const char*)As + byo);
      }
      #pragma unroll
      for (int j = 0; j < 4; j++){
        int row = wc*64 + j*16 + fr;
        int byo = row*128 + ((h*64 + kc*16) ^ ((row & 7) << 4));
        bw[j] = *(const bf16x8*)((const char*)Ws + byo);
      }
      #pragma unroll
      for (int i = 0; i < 4; i++)
        #pragma unroll
        for (int j = 0; j < 4; j++)
          acc[i][j] = __builtin_amdgcn_mfma_f32_16x16x32_bf16(bw[j], af[i], acc[i][j], 0, 0, 0);
    }
    __syncthreads();
  }

  float alpha = 1.f;
  if (MODE == 4) alpha = 0.5f*expf(-mtl[(long)s*3 + mtlIdx]);
  int ccol = lane & 15, cr4 = (lane >> 4)*4;
  bool vecN = ((Nc & 3) == 0);
  float* Cf = (float*)Cv + (long)s*sC;
  ushort* Cb = (ushort*)Cv + (long)s*sC;
  #pragma unroll
  for (int i = 0; i < 4; i++){
    int gm = m0 + wr*64 + i*16 + ccol;
    if (gm >= M) continue;
    long rowoff = (long)gm*ldc;
    #pragma unroll
    for (int j = 0; j < 4; j++){
      int gn0 = n0 + wc*64 + j*16 + cr4;
      if (gn0 >= Nc) continue;
      f32x4 v = acc[i][j];
      if (MODE != 4 && MODE != 2 && bias){ f32x4 bv = *(const f32x4*)&bias[gn0]; v += bv; }
      if (MODE == 1){ v = (f32x4){fmaxf(v[0],0.f),fmaxf(v[1],0.f),fmaxf(v[2],0.f),fmaxf(v[3],0.f)}; }
      if (OBF){
        u16x4* cp = (u16x4*)&Cb[rowoff + gn0];
        if (MODE == 4 || MODE == 2){
          u16x4 o = *cp;
          float a = (MODE == 4) ? alpha : 1.f;
          *cp = (u16x4){f2b(b2f(o[0]) + a*v[0]), f2b(b2f(o[1]) + a*v[1]),
                        f2b(b2f(o[2]) + a*v[2]), f2b(b2f(o[3]) + a*v[3])};
        } else {
          *cp = (u16x4){f2b(v[0]), f2b(v[1]), f2b(v[2]), f2b(v[3])};
        }
      } else {
        if (vecN){
          f32x4* cp = (f32x4*)&Cf[rowoff + gn0];
          if (MODE == 4){ f32x4 o = *cp; *cp = o + alpha*v; }
          else if (MODE == 2){ f32x4 o = *cp; *cp = o + v; }
          else *cp = v;
        } else {
          #pragma unroll
          for (int r = 0; r < 4; r++){
            int gn = gn0 + r; if (gn >= Nc) continue;
            if (MODE == 4) Cf[rowoff + gn] += alpha*v[r];
            else if (MODE == 2) Cf[rowoff + gn] += v[r];
            else Cf[rowoff + gn] = v[r];
          }
        }
      }
    }
  }
}

// ================= 3x3 attention: one wave per (seq, head) =================
__global__ void __launch_bounds__(256) attn_k(const ushort* __restrict__ qkv,
                                              ushort* __restrict__ o){
  int s = blockIdx.z;
  int w = threadIdx.x >> 6, lane = threadIdx.x & 63;
  int seq = blockIdx.x*2 + (w >> 1);
  int h = w & 1;
  const ushort* base = qkv + (long)s*QKV_S + (long)seq*3*1536 + h*256 + lane*4;
  float q[3][4], k[3][4], v[3][4];
  #pragma unroll
  for (int i = 0; i < 3; i++){
    u16x4 tq = *(const u16x4*)(base + (long)i*1536);
    u16x4 tk = *(const u16x4*)(base + (long)i*1536 + 512);
    u16x4 tv = *(const u16x4*)(base + (long)i*1536 + 1024);
    #pragma unroll
    for (int e = 0; e < 4; e++){ q[i][e]=b2f(tq[e]); k[i][e]=b2f(tk[e]); v[i][e]=b2f(tv[e]); }
  }
  float p[9];
  #pragma unroll
  for (int i = 0; i < 3; i++)
    #pragma unroll
    for (int j = 0; j < 3; j++){
      float acc = 0.f;
      #pragma unroll
      for (int e = 0; e < 4; e++) acc += q[i][e]*k[j][e];
      p[i*3+j] = acc;
    }
  #pragma unroll
  for (int m = 1; m < 64; m <<= 1)
    #pragma unroll
    for (int t = 0; t < 9; t++) p[t] += __shfl_xor(p[t], m);
  float att[9];
  #pragma unroll
  for (int i = 0; i < 3; i++){
    float a = p[i*3]*0.0625f, bb = p[i*3+1]*0.0625f, c = p[i*3+2]*0.0625f;
    float mx = fmaxf(a, fmaxf(bb, c));
    a = expf(a-mx); bb = expf(bb-mx); c = expf(c-mx);
    float inv = 1.f/(a+bb+c);
    att[i*3] = a*inv; att[i*3+1] = bb*inv; att[i*3+2] = c*inv;
  }
  ushort* ob = o + (long)s*Z_S + (long)seq*1536 + h*256 + lane*4;
  #pragma unroll
  for (int i = 0; i < 3; i++){
    u16x4 r;
    #pragma unroll
    for (int e = 0; e < 4; e++)
      r[e] = f2b(att[i*3]*v[0][e] + att[i*3+1]*v[1][e] + att[i*3+2]*v[2][e]);
    *(u16x4*)(ob + (long)i*512) = r;
  }
}

// ================= z = LN(res + t): one wave per row =================
__global__ void __launch_bounds__(256) add_ln_k(ushort* __restrict__ zout, long sZ,
                         const ushort* __restrict__ res, long sR, int mapN, int mapOff,
                         const ushort* __restrict__ tb, long sT,
                         const float* __restrict__ w, const float* __restrict__ b,
                         long wstr){
  int s = blockIdx.z;
  int wv = threadIdx.x >> 6, lane = threadIdx.x & 63;
  int r = blockIdx.x*4 + wv;
  int g = r;
  if (mapN > 0){ int tr = r / mapN; g = tr*NPT + mapOff + (r - tr*mapN); }
  int d0 = lane*8;
  u16x8 rr = *(const u16x8*)(res + (long)s*sR + (long)g*HH + d0);
  u16x8 tt = *(const u16x8*)(tb  + (long)s*sT + (long)r*HH + d0);
  float x[8];
  float sum = 0.f;
  #pragma unroll
  for (int e = 0; e < 8; e++){ x[e] = b2f(rr[e]) + b2f(tt[e]); sum += x[e]; }
  #pragma unroll
  for (int m = 1; m < 64; m <<= 1) sum += __shfl_xor(sum, m);
  float mean = sum * (1.f/512.f);
  float vs = 0.f;
  #pragma unroll
  for (int e = 0; e < 8; e++){ float d = x[e]-mean; vs += d*d; }
  #pragma unroll
  for (int m = 1; m < 64; m <<= 1) vs += __shfl_xor(vs, m);
  float inv = 1.f/sqrtf(vs*(1.f/512.f) + 1e-5f);
  const float* wr_ = w + (long)s*wstr + d0;
  const float* br_ = b + (long)s*wstr + d0;
  f32x4 w0 = *(const f32x4*)wr_, w1 = *(const f32x4*)(wr_+4);
  f32x4 b0 = *(const f32x4*)br_, b1 = *(const f32x4*)(br_+4);
  u16x8 ov;
  #pragma unroll
  for (int e = 0; e < 4; e++){
    ov[e]   = f2b((x[e]-mean)*inv*w0[e] + b0[e]);
    ov[e+4] = f2b((x[e+4]-mean)*inv*w1[e] + b1[e]);
  }
  *(u16x8*)(zout + (long)s*sZ + (long)r*HH + d0) = ov;
}

// ================= leaf LSTM cell =================
__global__ void leaf_k(const ushort* __restrict__ iou, const float* __restrict__ c0,
                       ushort* __restrict__ hbuf, float* __restrict__ cbuf){
  int s = blockIdx.z, p = blockIdx.x;
  int tree = p / 729, j = p - tree*729;
  long row = (long)(tree*NPT + 364 + j)*HH;
  const ushort* iour = iou + (long)s*QKV_S + (long)p*1536;
  const float* c0r = c0 + (long)s*H_S + row;
  for (int d = threadIdx.x; d < HH; d += 256){
    float cn = sigm(b2f(iour[d])) * tanhf(b2f(iour[1024 + d])) + c0r[d];
    float hn = sigm(b2f(iour[512 + d])) * tanhf(cn);
    hbuf[(long)s*H_S + row + d] = f2b(hn);
    cbuf[(long)s*H_S + row + d] = cn;
  }
}

// ================= internal-node combine =================
__global__ void combine_k(const ushort* __restrict__ wxiou, const ushort* __restrict__ z,
                          const float* __restrict__ bfv, const float* __restrict__ cbuf,
                          ushort* __restrict__ hbuf, float* __restrict__ cout,
                          int n, int st, int cs){
  int s = blockIdx.z, p = blockIdx.x;
  int tree = p / n, j = p - tree*n;
  const ushort* wr_ = wxiou + (long)s*WXI_S + (long)p*2048;
  const ushort* zr  = z + (long)s*Z_S + (long)p*1536;
  const float* bfr  = bfv + (long)s*HH;
  const float* cch  = cbuf + (long)s*H_S + (long)(tree*NPT + cs + 3*j)*HH;
  long orow = (long)s*H_S + (long)(tree*NPT + st + j)*HH;
  for (int d = threadIdx.x; d < HH; d += 256){
    float wv = b2f(wr_[d]) + bfr[d];
    float cpre = 0.f;
    #pragma unroll
    for (int ch = 0; ch < 3; ch++){
      float fg = sigm(wv + b2f(zr[ch*512 + d]));
      cpre += fg * cch[ch*512 + d];
    }
    float iv = b2f(wr_[512 + d]), ov = b2f(wr_[1024 + d]), uv = b2f(wr_[1536 + d]);
    float cn = sigm(iv)*tanhf(uv) + cpre;
    float hn = sigm(ov)*tanhf(cn);
    hbuf[orow + d] = f2b(hn);
    cout[orow + d] = cn;
  }
}

// launch helpers
#define GEMM(MODE, OBF, A1, LDA1, SA1, A2, LDA2, SA2, KSPL, MAPN, MAPOFF, WT, LDW, SW, \
             BI, SB, CC, LDC, SC, M, NC, K)                                            \
  do { int nbx_ = ((NC)+127)/128, nby_ = ((M)+127)/128;                                \
    mgemm_k<MODE, OBF><<<dim3(nbx_*nby_, 1, SIDES), 256, 0, stream>>>(                 \
      A1, LDA1, SA1, A2, LDA2, SA2, KSPL, MAPN, MAPOFF, WT, LDW, SW, BI, SB,           \
      CC, LDC, SC, M, NC, K, nbx_, mtl, 0); } while(0)

extern "C" void kernel_launch(void* const* d_in, const int* in_sizes, int n_in,
                              void* d_out, int out_size, void* d_ws, size_t ws_size,
                              hipStream_t stream){
  (void)in_sizes; (void)n_in; (void)out_size; (void)ws_size;
  const int*   user_ids  = (const int*)d_in[0];
  const int*   feat_ids  = (const int*)d_in[1];
  const int*   time_ids  = (const int*)d_in[2];
  const int*   mask      = (const int*)d_in[3];
  const float* user_emb  = (const float*)d_in[6];
  const float* fuse_emb  = (const float*)d_in[7];
  const float* time_pe   = (const float*)d_in[8];
  const float* Wf        = (const float*)d_in[9];
  const float* bf        = (const float*)d_in[10];
  const float* Wiou      = (const float*)d_in[11];
  const float* Uiou      = (const float*)d_in[12];
  const float* biou      = (const float*)d_in[13];
  const float* attn_in_w = (const float*)d_in[14];
  const float* attn_in_b = (const float*)d_in[15];
  const float* attn_out_w= (const float*)d_in[16];
  const float* attn_out_b= (const float*)d_in[17];
  const float* ff1_w     = (const float*)d_in[18];
  const float* ff1_b     = (const float*)d_in[19];
  const float* ff2_w     = (const float*)d_in[20];
  const float* ff2_b     = (const float*)d_in[21];
  const float* ln1_w     = (const float*)d_in[22];
  const float* ln1_b     = (const float*)d_in[23];
  const float* ln2_w     = (const float*)d_in[24];
  const float* ln2_b     = (const float*)d_in[25];
  const float* dec_poi_w = (const float*)d_in[26];
  const float* dec_poi_b = (const float*)d_in[27];
  const float* dec_cat_w = (const float*)d_in[28];
  const float* dec_cat_b = (const float*)d_in[29];
  const float* dec_coo_w = (const float*)d_in[30];
  const float* dec_coo_b = (const float*)d_in[31];
  const float* cat2poi_w = (const float*)d_in[32];
  const float* cat2poi_b = (const float*)d_in[33];
  const float* coo2poi_w = (const float*)d_in[34];
  const float* coo2poi_b = (const float*)d_in[35];
  const float* mtl       = (const float*)d_in[36];
  const float* c0        = (const float*)d_in[37];

  float* out = (float*)d_out;

  // ---- ws layout (bf16 persistent: Hb, weights) ----
  ushort* wsu = (ushort*)d_ws;
  ushort* Hb    = wsu;                         // [2][NN*512]
  ushort* ainW  = Hb    + 2*H_S;               // [2][2][1536*512]
  ushort* aoutW = ainW  + (long)2*2*1536*512;  // [2][2][512*512]
  ushort* f1W   = aoutW + (long)2*2*512*512;
  ushort* f2W   = f1W   + (long)2*2*512*512;
  ushort* wcomb = f2W   + (long)2*2*512*512;   // [2][2048*1792]
  ushort* dcatW = wcomb + (long)2*2048*1792;   // [2][300*512]
  ushort* dcooW = dcatW + (long)2*300*512;     // [2][50*512]
  ushort* weffB = dcooW + (long)2*50*512;      // [2][5000*512]
  float*  bcomb = (float*)(weffB + (long)2*WEFF_S);  // [2][2048]
  float*  beff  = bcomb + 2*2048;              // [2][5000]

  // ---- out-scratch (side-1 poi region; dead before final GEMM writes it) ----
  float*  Cb   = out + OUT_S;                  // [2][NN*512] f32
  ushort* osu  = (ushort*)(Cb + 2*H_S);
  ushort* QKV  = osu;                          // [2][TOKMAX*1536]
  ushort* Zb   = QKV  + 2*QKV_S;               // [2][TOKMAX*512]
  ushort* TMP  = Zb   + 2*Z_S;
  ushort* WXI  = TMP  + 2*Z_S;                 // [2][PARMAX*2048]
  ushort* Xb   = WXI  + 2*WXI_S;               // [2][NN*256]
  ushort* c2pB = Xb   + 2*X_S;                 // [2][5000*320]
  ushort* o2pB = c2pB + (long)2*5000*320;      // [2][5000*64]
  ushort* dcT2 = o2pB + (long)2*5000*64;       // [2][512*384]

  // ---- merged prep (preconvert + embed) ----
  prep_k<<<dim3(PB_TOT), 256, 0, stream>>>(
      user_ids, feat_ids, time_ids, mask, user_emb, fuse_emb, time_pe, Xb,
      ainW, attn_in_w, aoutW, attn_out_w, f1W, ff1_w, f2W, ff2_w,
      dcatW, dec_cat_w, dcooW, dec_coo_w,
      wcomb, Wf, Wiou, Uiou, bcomb, biou,
      c2pB, cat2poi_w, o2pB, coo2poi_w, dcT2,
      weffB, dec_poi_w, mtl,
      beff, dec_poi_b, dec_cat_b, cat2poi_b, dec_coo_b, coo2poi_b);

  // ---- leaves ----
  GEMM(0, true, Xb, 256L, X_S, Xb, 256L, X_S, 256, 729, 364,
       wcomb + (long)512*1792, 1792L, (long)2048*1792,
       (const float*)nullptr, 0L, QKV, 1536L, QKV_S, 5832, 1536, 256);
  leaf_k<<<dim3(5832, 1, SIDES), 256, 0, stream>>>(QKV, c0, Hb, Cb);

  const int p3[7]   = {1,3,9,27,81,243,729};
  const int offs[7] = {0,1,4,13,40,121,364};

  // ---- internal levels ----
  for (int l = 5; l >= 0; l--){
    int n = p3[l], st = offs[l], cs = offs[l+1];
    int P = NTREE*n, T = 3*P;
    for (int L = 0; L < LAYERS; L++){
      const ushort* zin = (L == 0) ? Hb : Zb;
      long zs = (L == 0) ? H_S : Z_S;
      int mN = (L == 0) ? 3*n : 0, mO = (L == 0) ? cs : 0;
      GEMM(0, true, zin, 512L, zs, zin, 512L, zs, 512, mN, mO,
           ainW + (long)L*1536*512, 512L, (long)2*1536*512,
           attn_in_b + (long)L*1536, (long)LAYERS*1536, QKV, 1536L, QKV_S, T, 1536, 512);
      attn_k<<<dim3(P/2, 1, SIDES), 256, 0, stream>>>(QKV, TMP);
      GEMM(0, true, TMP, 512L, Z_S, TMP, 512L, Z_S, 512, 0, 0,
           aoutW + (long)L*512*512, 512L, (long)2*512*512,
           attn_out_b + (long)L*512, (long)LAYERS*512, QKV, 512L, QKV_S, T, 512, 512);
      add_ln_k<<<dim3(T/4, 1, SIDES), 256, 0, stream>>>(Zb, Z_S, zin, zs, mN, mO,
           QKV, QKV_S, ln1_w + (long)L*512, ln1_b + (long)L*512, (long)LAYERS*512);
      GEMM(1, true, Zb, 512L, Z_S, Zb, 512L, Z_S, 512, 0, 0,
           f1W + (long)L*512*512, 512L, (long)2*512*512,
           ff1_b + (long)L*512, (long)LAYERS*512, TMP, 512L, Z_S, T, 512, 512);
      GEMM(0, true, TMP, 512L, Z_S, TMP, 512L, Z_S, 512, 0, 0,
           f2W + (long)L*512*512, 512L, (long)2*512*512,
           ff2_b + (long)L*512, (long)LAYERS*512, QKV, 512L, QKV_S, T, 512, 512);
      add_ln_k<<<dim3(T/4, 1, SIDES), 256, 0, stream>>>(Zb, Z_S, Zb, Z_S, 0, 0,
           QKV, QKV_S, ln2_w + (long)L*512, ln2_b + (long)L*512, (long)LAYERS*512);
    }
    // [wx | iou] = [x | z] @ [Wf|0 ; Wiou|Uiou]^T + [0|biou]
    GEMM(0, true, Xb, 256L, X_S, Zb, 1536L, Z_S, 256, n, st,
         wcomb, 1792L, (long)2048*1792, bcomb, 2048L, WXI, 2048L, WXI_S, P, 2048, 1792);
    combine_k<<<dim3(P, 1, SIDES), 256, 0, stream>>>(WXI, Zb, bf, Cb, Hb, Cb, n, st, cs);
  }

  // ---- cat/coo decoders ----
  GEMM(0, false, Hb, 512L, H_S, Hb, 512L, H_S, 512, 0, 0,
       dcatW, 512L, (long)NCAT*512, dec_cat_b, (long)NCAT,
       out + CAT_OFF, (long)NCAT, OUT_S, NN, NCAT, 512);
  GEMM(0, false, Hb, 512L, H_S, Hb, 512L, H_S, 512, 0, 0,
       dcooW, 512L, (long)NCOO*512, dec_coo_b, (long)NCOO,
       out + COO_OFF, (long)NCOO, OUT_S, NN, NCOO, 512);

  // ---- Weff += a1*cat2poi@dec_cat^T + a2*coo2poi@dec_coo^T (one dual-source GEMM) ----
  GEMM(2, true, c2pB, 320L, (long)5000*320, o2pB, 64L, (long)5000*64, 320, 0, 0,
       dcT2, 384L, (long)512*384, (const float*)nullptr, 0L,
       weffB, 512L, WEFF_S, 5000, 512, 384);

  // ---- fused poi decoder ----
  GEMM(0, false, Hb, 512L, H_S, Hb, 512L, H_S, 512, 0, 0,
       weffB, 512L, WEFF_S, beff, (long)NPOI,
       out, (long)NPOI, OUT_S, NN, NPOI, 512);
}